// Round 1
// baseline (115.536 us; speedup 1.0000x reference)
//
#include <hip/hip_runtime.h>
#include <math.h>

// E8 quantizer, structured-codebook version.
// - 112 integer roots (±e_i ±e_j): dot = ±x_i ± x_j, accumulated directly.
// - 128 half-roots 0.5*sigma (even # of minus signs): sigma split into two
//   4-bit halves; dots via two 16-entry sign-sum butterflies; weights
//   accumulated into per-half-pattern sums W[p], V[q]; output components
//   recovered by adjoint fold.
// - All roots have |c|^2 = 2 -> constant cancels in softmax; logit = 2*dot/T.
// - Stability shift M = 2*sqrt(2)*|x|/T >= max logit (Cauchy-Schwarz); some
//   root always has cos >= 0.5 so denominator >= ~2^-50: no underflow.

static constexpr float TEMP = 0.3f;

__device__ __forceinline__ float fexp2(float v) { return __builtin_amdgcn_exp2f(v); }

__global__ __launch_bounds__(256) void e8_quant_kernel(
    const float* __restrict__ x, float* __restrict__ out, int n)
{
    int tid = blockIdx.x * blockDim.x + threadIdx.x;
    if (tid >= n) return;

    const float4 xa = reinterpret_cast<const float4*>(x)[tid * 2 + 0];
    const float4 xb = reinterpret_cast<const float4*>(x)[tid * 2 + 1];
    float xv[8] = {xa.x, xa.y, xa.z, xa.w, xb.x, xb.y, xb.z, xb.w};

    const float K = 2.0f * 1.44269504088896340736f / TEMP;  // 2*log2(e)/T: exp2 units
    float nrm2 = 0.f;
#pragma unroll
    for (int k = 0; k < 8; ++k) nrm2 = fmaf(xv[k], xv[k], nrm2);
    const float r = sqrtf(nrm2);
    const float C = -1.41421356237309515f * r * K;  // shift so exp2 args <= 0

    // ---- sign-sum butterflies: s01[t] = (bit0?-:+)x0 + (bit1?-:+)x1, etc. ----
    float s01[4], s23[4], s45[4], s67[4];
    s01[0] = xv[0] + xv[1]; s01[1] = xv[1] - xv[0]; s01[2] = xv[0] - xv[1]; s01[3] = -s01[0];
    s23[0] = xv[2] + xv[3]; s23[1] = xv[3] - xv[2]; s23[2] = xv[2] - xv[3]; s23[3] = -s23[0];
    s45[0] = xv[4] + xv[5]; s45[1] = xv[5] - xv[4]; s45[2] = xv[4] - xv[5]; s45[3] = -s45[0];
    s67[0] = xv[6] + xv[7]; s67[1] = xv[7] - xv[6]; s67[2] = xv[6] - xv[7]; s67[3] = -s67[0];

    // A[p] = a_p*(K/2) + C,  B[q] = b_q*(K/2);  exp2 arg for half-root = A[p]+B[q]
    float A[16], B[16];
    const float Kh = K * 0.5f;
#pragma unroll
    for (int p = 0; p < 16; ++p) {
        A[p] = fmaf(s01[p & 3] + s23[p >> 2], Kh, C);
        B[p] = (s45[p & 3] + s67[p >> 2]) * Kh;
    }

    // ---- 128 half-integer roots: even total minus-count <=> parity(p)==parity(q)
    float W[16], V[16];
#pragma unroll
    for (int p = 0; p < 16; ++p) { W[p] = 0.f; V[p] = 0.f; }
#pragma unroll
    for (int p = 0; p < 16; ++p) {
#pragma unroll
        for (int q = 0; q < 16; ++q) {
            if ((__builtin_popcount(p ^ q) & 1) == 0) {  // compile-time constant
                float w = fexp2(A[p] + B[q]);
                W[p] += w;
                V[q] += w;
            }
        }
    }

    // adjoint fold: comp[j] = sum_p sign(p,j) * W[p]   (sign = -1 if bit j set)
    float FA01[4], FA23[4], FB01[4], FB23[4];
#pragma unroll
    for (int t = 0; t < 4; ++t) { FA01[t] = 0.f; FA23[t] = 0.f; FB01[t] = 0.f; FB23[t] = 0.f; }
#pragma unroll
    for (int p = 0; p < 16; ++p) {
        FA01[p & 3] += W[p];
        FA23[p >> 2] += W[p];
        FB01[p & 3] += V[p];
        FB23[p >> 2] += V[p];
    }
    float s2sum = (FA01[0] + FA01[1]) + (FA01[2] + FA01[3]);
    float comp[8];
    comp[0] = (FA01[0] - FA01[1]) + (FA01[2] - FA01[3]);
    comp[1] = (FA01[0] + FA01[1]) - (FA01[2] + FA01[3]);
    comp[2] = (FA23[0] - FA23[1]) + (FA23[2] - FA23[3]);
    comp[3] = (FA23[0] + FA23[1]) - (FA23[2] + FA23[3]);
    comp[4] = (FB01[0] - FB01[1]) + (FB01[2] - FB01[3]);
    comp[5] = (FB01[0] + FB01[1]) - (FB01[2] + FB01[3]);
    comp[6] = (FB23[0] - FB23[1]) + (FB23[2] - FB23[3]);
    comp[7] = (FB23[0] + FB23[1]) - (FB23[2] + FB23[3]);

    // ---- 112 integer roots ±e_i ±e_j ----
    float acc[8];
#pragma unroll
    for (int k = 0; k < 8; ++k) acc[k] = 0.f;
    float ssum = s2sum;
#pragma unroll
    for (int i = 0; i < 8; ++i) {
#pragma unroll
        for (int j = i + 1; j < 8; ++j) {
#pragma unroll
            for (int sgn = 0; sgn < 2; ++sgn) {
                float u = sgn ? (xv[i] - xv[j]) : (xv[i] + xv[j]);
                float wp = fexp2(fmaf(u, K, C));   // weight of +(e_i (+/-) e_j)
                float wm = fexp2(fmaf(-u, K, C));  // weight of -(e_i (+/-) e_j)
                float dw = wp - wm;
                ssum += wp + wm;
                acc[i] += dw;
                acc[j] += sgn ? -dw : dw;
            }
        }
    }

    // combine, normalize, STE-mimicking output
#pragma unroll
    for (int k = 0; k < 8; ++k) acc[k] = fmaf(0.5f, comp[k], acc[k]);
    const float inv = 1.0f / ssum;
    float outv[8];
#pragma unroll
    for (int k = 0; k < 8; ++k) {
        float q = acc[k] * inv;
        outv[k] = xv[k] + (q - xv[k]);  // matches reference x + (quantized - x)
    }
    float4 oa = {outv[0], outv[1], outv[2], outv[3]};
    float4 ob = {outv[4], outv[5], outv[6], outv[7]};
    reinterpret_cast<float4*>(out)[tid * 2 + 0] = oa;
    reinterpret_cast<float4*>(out)[tid * 2 + 1] = ob;
}

extern "C" void kernel_launch(void* const* d_in, const int* in_sizes, int n_in,
                              void* d_out, int out_size, void* d_ws, size_t ws_size,
                              hipStream_t stream) {
    const float* x = (const float*)d_in[0];
    float* out = (float*)d_out;
    const int n = in_sizes[0] / 8;
    const int block = 256;
    const int grid = (n + block - 1) / block;
    hipLaunchKernelGGL(e8_quant_kernel, dim3(grid), dim3(block), 0, stream, x, out, n);
}

// Round 2
// 87.123 us; speedup vs baseline: 1.3261x; 1.3261x over previous
//
#include <hip/hip_runtime.h>
#include <math.h>

// E8 quantizer, structured-codebook + factored-exp version.
// logit(root) = K*dot(x,root) + C  in exp2 units, K = 2*log2(e)/T,
// C = -sqrt(2)*|x|*K  (Cauchy-Schwarz shift, all args <= 0).
// Every root's weight factors into per-coordinate-group exponentials:
//   integer roots +-e_i +-e_j : w = E_i(s)*E_j(s'),  E_i(s)=exp2(s*K*x_i + C/2)
//   half roots 0.5*sigma      : w = EA[p]*EB[q],     EA[p]=e01[p&3]*e23[p>>2]
// -> 32 exp2 per point instead of 240, and the parity-constrained half-root
// sum collapses to two positive 8-term sums per side.
// All aggregate sums are positive-term prefix/suffix sums (NO Ptot-Pi style
// subtraction -> no catastrophic cancellation when one coordinate dominates).

static constexpr float TEMP = 0.3f;

__device__ __forceinline__ float fexp2(float v) { return __builtin_amdgcn_exp2f(v); }
__device__ __forceinline__ float frcp(float v) { return __builtin_amdgcn_rcpf(v); }

__global__ __launch_bounds__(256) void e8_quant_kernel(
    const float* __restrict__ x, float* __restrict__ out, int n)
{
    int tid = blockIdx.x * blockDim.x + threadIdx.x;
    if (tid >= n) return;

    const float4 xa = reinterpret_cast<const float4*>(x)[tid * 2 + 0];
    const float4 xb = reinterpret_cast<const float4*>(x)[tid * 2 + 1];
    float xv[8] = {xa.x, xa.y, xa.z, xa.w, xb.x, xb.y, xb.z, xb.w};

    const float K  = 2.0f * 1.44269504088896340736f / TEMP;  // exp2 units
    const float Kh = 0.5f * K;
    float nrm2 = 0.f;
#pragma unroll
    for (int k = 0; k < 8; ++k) nrm2 = fmaf(xv[k], xv[k], nrm2);
    const float r  = sqrtf(nrm2);
    const float C  = -1.41421356237309515f * r * K;
    const float C2 = 0.5f * C;
    const float C4 = 0.25f * C;

    // ---- sign-sum butterflies: bit set => that coord negated ----
    float s01[4], s23[4], s45[4], s67[4];
    s01[0] = xv[0] + xv[1]; s01[1] = xv[1] - xv[0]; s01[2] = xv[0] - xv[1]; s01[3] = -s01[0];
    s23[0] = xv[2] + xv[3]; s23[1] = xv[3] - xv[2]; s23[2] = xv[2] - xv[3]; s23[3] = -s23[0];
    s45[0] = xv[4] + xv[5]; s45[1] = xv[5] - xv[4]; s45[2] = xv[4] - xv[5]; s45[3] = -s45[0];
    s67[0] = xv[6] + xv[7]; s67[1] = xv[7] - xv[6]; s67[2] = xv[6] - xv[7]; s67[3] = -s67[0];

    // ---- factored exponentials for half-roots: 16 exp total ----
    float e01[4], e23[4], e45[4], e67[4];
#pragma unroll
    for (int t = 0; t < 4; ++t) {
        e01[t] = fexp2(fmaf(s01[t], Kh, C4));
        e23[t] = fexp2(fmaf(s23[t], Kh, C4));
        e45[t] = fexp2(fmaf(s45[t], Kh, C4));
        e67[t] = fexp2(fmaf(s67[t], Kh, C4));
    }

    float EA[16], EB[16];
#pragma unroll
    for (int p = 0; p < 16; ++p) {
        EA[p] = e01[p & 3] * e23[p >> 2];  // = exp2(a_p*Kh + C/2)
        EB[p] = e45[p & 3] * e67[p >> 2];  // = exp2(b_p*Kh + C/2)
    }

    // parity-split positive sums
    float SAe = 0.f, SAo = 0.f, SBe = 0.f, SBo = 0.f;
#pragma unroll
    for (int p = 0; p < 16; ++p) {
        if (__builtin_popcount(p) & 1) { SAo += EA[p]; SBo += EB[p]; }
        else                           { SAe += EA[p]; SBe += EB[p]; }
    }

    // W[p] = sum over matching-parity q of EA[p]*EB[q]; V[q] symmetric
    float W[16], V[16];
#pragma unroll
    for (int p = 0; p < 16; ++p) {
        const bool odd = (__builtin_popcount(p) & 1) != 0;
        W[p] = EA[p] * (odd ? SBo : SBe);
        V[p] = EB[p] * (odd ? SAo : SAe);
    }

    // adjoint fold: comp[j] = sum_p sign(p,j) * W[p]  (bit j set => minus)
    float FA01[4], FA23[4], FB01[4], FB23[4];
#pragma unroll
    for (int t = 0; t < 4; ++t) { FA01[t] = 0.f; FA23[t] = 0.f; FB01[t] = 0.f; FB23[t] = 0.f; }
#pragma unroll
    for (int p = 0; p < 16; ++p) {
        FA01[p & 3]  += W[p];
        FA23[p >> 2] += W[p];
        FB01[p & 3]  += V[p];
        FB23[p >> 2] += V[p];
    }
    const float s2sum = (FA01[0] + FA01[1]) + (FA01[2] + FA01[3]);
    float comp[8];
    comp[0] = (FA01[0] - FA01[1]) + (FA01[2] - FA01[3]);
    comp[1] = (FA01[0] + FA01[1]) - (FA01[2] + FA01[3]);
    comp[2] = (FA23[0] - FA23[1]) + (FA23[2] - FA23[3]);
    comp[3] = (FA23[0] + FA23[1]) - (FA23[2] + FA23[3]);
    comp[4] = (FB01[0] - FB01[1]) + (FB01[2] - FB01[3]);
    comp[5] = (FB01[0] + FB01[1]) - (FB01[2] + FB01[3]);
    comp[6] = (FB23[0] - FB23[1]) + (FB23[2] - FB23[3]);
    comp[7] = (FB23[0] + FB23[1]) - (FB23[2] + FB23[3]);

    // ---- 112 integer roots via 16 factored exps ----
    float P[8], D[8];
#pragma unroll
    for (int i = 0; i < 8; ++i) {
        const float ep = fexp2(fmaf(xv[i],  K, C2));
        const float em = fexp2(fmaf(-xv[i], K, C2));
        P[i] = ep + em;
        D[i] = ep - em;
    }
    // positive prefix/suffix sums (avoid Ptot - Pi cancellation)
    float suf[9];
    suf[8] = 0.f;
#pragma unroll
    for (int i = 7; i >= 0; --i) suf[i] = suf[i + 1] + P[i];
    float pre = 0.f, ssum_int = 0.f;
    float acc[8];
#pragma unroll
    for (int i = 0; i < 8; ++i) {
        const float Q = pre + suf[i + 1];          // sum_{j != i} P[j]
        acc[i] = D[i] * Q;
        ssum_int = fmaf(P[i], suf[i + 1], ssum_int);  // sum_{i<j} P_i P_j
        pre += P[i];
    }

    // ---- combine, normalize, STE-mimicking output ----
    const float ssum = ssum_int + s2sum;
    const float inv  = frcp(ssum);
    float outv[8];
#pragma unroll
    for (int k = 0; k < 8; ++k) {
        const float total = fmaf(0.5f, comp[k], acc[k]);
        const float q = total * inv;
        outv[k] = xv[k] + (q - xv[k]);  // matches reference x + (quantized - x)
    }
    float4 oa = {outv[0], outv[1], outv[2], outv[3]};
    float4 ob = {outv[4], outv[5], outv[6], outv[7]};
    reinterpret_cast<float4*>(out)[tid * 2 + 0] = oa;
    reinterpret_cast<float4*>(out)[tid * 2 + 1] = ob;
}

extern "C" void kernel_launch(void* const* d_in, const int* in_sizes, int n_in,
                              void* d_out, int out_size, void* d_ws, size_t ws_size,
                              hipStream_t stream) {
    const float* x = (const float*)d_in[0];
    float* out = (float*)d_out;
    const int n = in_sizes[0] / 8;
    const int block = 256;
    const int grid = (n + block - 1) / block;
    hipLaunchKernelGGL(e8_quant_kernel, dim3(grid), dim3(block), 0, stream, x, out, n);
}

// Round 3
// 83.396 us; speedup vs baseline: 1.3854x; 1.0447x over previous
//
#include <hip/hip_runtime.h>
#include <math.h>

// E8 quantizer, fully-factored version.
// logit(root) = K*dot(x,root) + C in exp2 units; K = 2*log2(e)/T,
// C = -sqrt(2)*|x|*K (Cauchy-Schwarz shift -> all exp2 args <= 0 in products).
//
// Integer roots +-e_i +-e_j (112): w = E_i(s)*E_j(s'), E_i(s)=exp2(s*K*x_i+C/2).
//   -> 16 exps; sums via positive prefix/suffix (no cancellation).
// Half roots 0.5*sigma, even parity (128): sigma split 2+2+2+2 coords.
//   e01[t] = exp2(Kh*s01[t]+C4) etc (16 exps). Pair sums:
//     G01e=e01[0]+e01[3], G01o=e01[1]+e01[2] (even/odd #minus in the pair)
//   Parity-split half sums: SAe=G01e*G23e+G01o*G23o, SAo=G01e*G23o+G01o*G23e,
//   likewise SB from G45,G67. Total: s2sum = SAe*SBe+SAo*SBo.
//   Signed component sums collapse to comp[0]=dA*M0+dB*M1, comp[1]=dA*M0-dB*M1
//   with dA=e01[0]-e01[3], dB=e01[2]-e01[1], M0=G23e*SBe+G23o*SBo,
//   M1=G23e*SBo+G23o*SBe (and symmetric for the other 3 pairs).
// Identical math to the previous passing kernel, ~90 fewer VALU ops/point.

static constexpr float TEMP = 0.3f;

__device__ __forceinline__ float fexp2(float v) { return __builtin_amdgcn_exp2f(v); }
__device__ __forceinline__ float frcp(float v) { return __builtin_amdgcn_rcpf(v); }

__global__ __launch_bounds__(256) void e8_quant_kernel(
    const float* __restrict__ x, float* __restrict__ out, int n)
{
    int tid = blockIdx.x * blockDim.x + threadIdx.x;
    if (tid >= n) return;

    const float4 xa = reinterpret_cast<const float4*>(x)[tid * 2 + 0];
    const float4 xb = reinterpret_cast<const float4*>(x)[tid * 2 + 1];
    float xv[8] = {xa.x, xa.y, xa.z, xa.w, xb.x, xb.y, xb.z, xb.w};

    const float K  = 2.0f * 1.44269504088896340736f / TEMP;  // exp2 units
    const float Kh = 0.5f * K;
    float nrm2 = 0.f;
#pragma unroll
    for (int k = 0; k < 8; ++k) nrm2 = fmaf(xv[k], xv[k], nrm2);
    const float r  = sqrtf(nrm2);
    const float C  = -1.41421356237309515f * r * K;
    const float C2 = 0.5f * C;
    const float C4 = 0.25f * C;

    // ---- per-pair exponentials for half-roots (16 exps) ----
    // index t: bit0 set => first coord negated, bit1 set => second negated
    float e01[4], e23[4], e45[4], e67[4];
    {
        const float u01 = xv[0] + xv[1], v01 = xv[1] - xv[0];
        const float u23 = xv[2] + xv[3], v23 = xv[3] - xv[2];
        const float u45 = xv[4] + xv[5], v45 = xv[5] - xv[4];
        const float u67 = xv[6] + xv[7], v67 = xv[7] - xv[6];
        e01[0] = fexp2(fmaf(u01, Kh, C4)); e01[3] = fexp2(fmaf(-u01, Kh, C4));
        e01[1] = fexp2(fmaf(v01, Kh, C4)); e01[2] = fexp2(fmaf(-v01, Kh, C4));
        e23[0] = fexp2(fmaf(u23, Kh, C4)); e23[3] = fexp2(fmaf(-u23, Kh, C4));
        e23[1] = fexp2(fmaf(v23, Kh, C4)); e23[2] = fexp2(fmaf(-v23, Kh, C4));
        e45[0] = fexp2(fmaf(u45, Kh, C4)); e45[3] = fexp2(fmaf(-u45, Kh, C4));
        e45[1] = fexp2(fmaf(v45, Kh, C4)); e45[2] = fexp2(fmaf(-v45, Kh, C4));
        e67[0] = fexp2(fmaf(u67, Kh, C4)); e67[3] = fexp2(fmaf(-u67, Kh, C4));
        e67[1] = fexp2(fmaf(v67, Kh, C4)); e67[2] = fexp2(fmaf(-v67, Kh, C4));
    }

    // pair even/odd sums and signed differences
    const float G01e = e01[0] + e01[3], G01o = e01[1] + e01[2];
    const float G23e = e23[0] + e23[3], G23o = e23[1] + e23[2];
    const float G45e = e45[0] + e45[3], G45o = e45[1] + e45[2];
    const float G67e = e67[0] + e67[3], G67o = e67[1] + e67[2];
    const float dA01 = e01[0] - e01[3], dB01 = e01[2] - e01[1];
    const float dA23 = e23[0] - e23[3], dB23 = e23[2] - e23[1];
    const float dA45 = e45[0] - e45[3], dB45 = e45[2] - e45[1];
    const float dA67 = e67[0] - e67[3], dB67 = e67[2] - e67[1];

    // parity-split half sums
    const float SAe = fmaf(G01e, G23e, G01o * G23o);
    const float SAo = fmaf(G01e, G23o, G01o * G23e);
    const float SBe = fmaf(G45e, G67e, G45o * G67o);
    const float SBo = fmaf(G45e, G67o, G45o * G67e);
    const float s2sum = fmaf(SAe, SBe, SAo * SBo);

    // per-pair parity multipliers
    const float M01e = fmaf(G23e, SBe, G23o * SBo), M01o = fmaf(G23e, SBo, G23o * SBe);
    const float M23e = fmaf(G01e, SBe, G01o * SBo), M23o = fmaf(G01e, SBo, G01o * SBe);
    const float M45e = fmaf(G67e, SAe, G67o * SAo), M45o = fmaf(G67e, SAo, G67o * SAe);
    const float M67e = fmaf(G45e, SAe, G45o * SAo), M67o = fmaf(G45e, SAo, G45o * SAe);

    float comp[8];
    {
        const float t0 = dA01 * M01e, t1 = dB01 * M01o;
        comp[0] = t0 + t1; comp[1] = t0 - t1;
        const float t2 = dA23 * M23e, t3 = dB23 * M23o;
        comp[2] = t2 + t3; comp[3] = t2 - t3;
        const float t4 = dA45 * M45e, t5 = dB45 * M45o;
        comp[4] = t4 + t5; comp[5] = t4 - t5;
        const float t6 = dA67 * M67e, t7 = dB67 * M67o;
        comp[6] = t6 + t7; comp[7] = t6 - t7;
    }

    // ---- 112 integer roots via 16 factored exps ----
    float P[8], D[8];
#pragma unroll
    for (int i = 0; i < 8; ++i) {
        const float ep = fexp2(fmaf(xv[i],  K, C2));
        const float em = fexp2(fmaf(-xv[i], K, C2));
        P[i] = ep + em;
        D[i] = ep - em;
    }
    float suf[9];
    suf[8] = 0.f;
#pragma unroll
    for (int i = 7; i >= 0; --i) suf[i] = suf[i + 1] + P[i];
    float pre = 0.f, ssum_int = 0.f;
    float acc[8];
#pragma unroll
    for (int i = 0; i < 8; ++i) {
        const float Q = pre + suf[i + 1];             // sum_{j != i} P[j]
        acc[i] = D[i] * Q;
        ssum_int = fmaf(P[i], suf[i + 1], ssum_int);  // sum_{i<j} P_i P_j
        pre += P[i];
    }

    // ---- combine, normalize, output (STE forward = quantized) ----
    const float ssum = ssum_int + s2sum;
    const float inv  = frcp(ssum);
    float outv[8];
#pragma unroll
    for (int k = 0; k < 8; ++k) {
        const float total = fmaf(0.5f, comp[k], acc[k]);
        const float q = total * inv;
        outv[k] = xv[k] + (q - xv[k]);  // matches reference x + (quantized - x)
    }
    float4 oa = {outv[0], outv[1], outv[2], outv[3]};
    float4 ob = {outv[4], outv[5], outv[6], outv[7]};
    reinterpret_cast<float4*>(out)[tid * 2 + 0] = oa;
    reinterpret_cast<float4*>(out)[tid * 2 + 1] = ob;
}

extern "C" void kernel_launch(void* const* d_in, const int* in_sizes, int n_in,
                              void* d_out, int out_size, void* d_ws, size_t ws_size,
                              hipStream_t stream) {
    const float* x = (const float*)d_in[0];
    float* out = (float*)d_out;
    const int n = in_sizes[0] / 8;
    const int block = 256;
    const int grid = (n + block - 1) / block;
    hipLaunchKernelGGL(e8_quant_kernel, dim3(grid), dim3(block), 0, stream, x, out, n);
}